// Round 14
// baseline (486.019 us; speedup 1.0000x reference)
//
#include <hip/hip_runtime.h>

#define NN 50000
#define NE 800000
#define D 128
#define MMB2 196  // ceil(NN/256) -- 256 rows per k_mm block
#define NBLK 196  // ceil(NN/256)

typedef __attribute__((ext_vector_type(8))) short short8;
typedef __attribute__((ext_vector_type(4))) float f32x4;

#define SWZ(b) ((b) ^ ((((b)>>8)&7)<<4))

__device__ __forceinline__ unsigned int f2bf(float f){
  unsigned int u = __float_as_uint(f);
  return (u + 0x7FFFu + ((u>>16)&1u)) >> 16;   // RNE fp32 -> bf16
}
__device__ __forceinline__ float bf2f(unsigned int u){
  return __uint_as_float(u<<16);
}
__device__ __forceinline__ unsigned int pk2(float lo, float hi){
  unsigned int r;
  asm("v_cvt_pk_bf16_f32 %0, %1, %2" : "=v"(r) : "v"(lo), "v"(hi));
  return r;
}

// ---------- CSR build ----------
__global__ void k_hist(const int* __restrict__ dst0, int* __restrict__ cnt){
  int id = blockIdx.x*256 + threadIdx.x;
  if(id < NE/4){
    int4 d = ((const int4*)dst0)[id];
    atomicAdd(&cnt[d.x],1); atomicAdd(&cnt[d.y],1);
    atomicAdd(&cnt[d.z],1); atomicAdd(&cnt[d.w],1);
  }
}

__global__ __launch_bounds__(256) void k_scanA(const int* __restrict__ cnt, int* __restrict__ bsum){
  __shared__ int sh[256];
  int b = blockIdx.x, t = threadIdx.x;
  int i = b*256 + t;
  int v = (i<NN) ? cnt[i] : 0;
  sh[t] = v; __syncthreads();
  for(int off=128; off>0; off>>=1){
    if(t<off) sh[t] += sh[t+off];
    __syncthreads();
  }
  if(t==0) bsum[b] = sh[0];
}

// folded scanB+scanC: each block redundantly scans the 196 block sums,
// then local exclusive scan -> rowptr; also dinv and cnt reset
__global__ __launch_bounds__(256) void k_scanC(const int* __restrict__ cnt, const int* __restrict__ bsum,
    int* __restrict__ rowptr, float* __restrict__ dinv, int* __restrict__ cntz){
  __shared__ int sh2[256];
  __shared__ int sh[256];
  int b = blockIdx.x, t = threadIdx.x;
  int v2 = (t<NBLK) ? bsum[t] : 0;
  sh2[t] = v2; __syncthreads();
  for(int off=1; off<256; off<<=1){
    int add = (t>=off) ? sh2[t-off] : 0;
    __syncthreads();
    sh2[t] += add;
    __syncthreads();
  }
  int base = (b>0) ? sh2[b-1] : 0;
  int i = b*256 + t;
  int v = (i<NN) ? cnt[i] : 0;
  sh[t] = v; __syncthreads();
  for(int off=1; off<256; off<<=1){
    int add = (t>=off) ? sh[t-off] : 0;
    __syncthreads();
    sh[t] += add;
    __syncthreads();
  }
  int excl = sh[t] - v;
  if(i<NN){
    rowptr[i] = base + excl;
    dinv[i] = rsqrtf((float)(v+1));
    cntz[i] = 0;
  }
  if(b==gridDim.x-1 && t==255) rowptr[NN] = NE;
}

__global__ void k_fill(const int* __restrict__ src0, const int* __restrict__ dst0,
                       const int* __restrict__ rowptr, int* __restrict__ cur,
                       int* __restrict__ csr_src, int2* __restrict__ csr_de){
  int e = blockIdx.x*256 + threadIdx.x;
  if(e<NE){
    int d = dst0[e];
    int pos = atomicAdd(&cur[d],1);
    int slot = rowptr[d]+pos;
    csr_src[slot] = src0[e];
    csr_de[slot] = make_int2(d, e);
  }
}

// all weight transposes+bf16 in one kernel
__global__ void k_prep_all(const float* __restrict__ W1, const float* __restrict__ W2,
    const float* __restrict__ W3, const float* __restrict__ Wc1, const float* __restrict__ Wc2,
    unsigned short* __restrict__ w1T, unsigned short* __restrict__ w2T,
    unsigned short* __restrict__ w3T, unsigned short* __restrict__ wc1aT,
    unsigned short* __restrict__ wc1bT, unsigned short* __restrict__ wc2T){
  int id = blockIdx.x*256 + threadIdx.x;
  if(id < 81920){
    int seg = id >> 14, q = id & 16383;
    int c = q>>7, k = q&127;
    const float* W; unsigned short* wT;
    switch(seg){
      case 0: W=W1; wT=w1T; break;
      case 1: W=W2; wT=w2T; break;
      case 2: W=W3; wT=w3T; break;
      case 3: W=Wc1; wT=wc1aT; break;
      default: W=Wc1+128*128; wT=wc1bT; break;
    }
    wT[q] = (unsigned short)f2bf(W[(size_t)k*128+c]);
  } else if(id < 90112){
    int q = id - 81920;
    int c = q>>7, k = q&127;
    wc2T[q] = (unsigned short)f2bf(Wc2[(size_t)k*64+c]);
  }
}

// ---------- node GEMM (bf16 MFMA): out = [bnrelu](in) @ W [*dinv] [+bias] ----------
// 256 rows per block: sW staged ONCE, then 4 sub-tiles {stage sA -> MFMA -> store}.
// BN scale/shift computed in-block from per-layer `sums` when non-null.
// Dual mode: grid = 2*halfGrid -> second half uses wTb/outb, no bias.
// Operand-swapped MFMA -> transposed C, direct 8B stores.
__global__ __launch_bounds__(256) void k_mm(const unsigned short* __restrict__ in,
    const float* __restrict__ in32,
    const unsigned short* __restrict__ wTa, const unsigned short* __restrict__ wTb,
    unsigned short* __restrict__ outa, unsigned short* __restrict__ outb,
    const float* __restrict__ sums, const float* __restrict__ g, const float* __restrict__ be,
    const float* __restrict__ dinv, const float* __restrict__ biasA, int halfGrid){
  __shared__ char sA[64*256];    // bf16 [64 rows][128], XOR-swizzled (16KB)
  __shared__ char sW[128*256];   // bf16 [128 cols][128 k], XOR-swizzled (32KB)
  __shared__ float sss[256];
  int t = threadIdx.x;
  int bid = blockIdx.x;
  bool second = bid >= halfGrid;
  int rb0 = (second ? bid-halfGrid : bid)*256;
  const unsigned short* wT = second ? wTb : wTa;
  unsigned short* outp = second ? outb : outa;
  const float* bias = second ? nullptr : biasA;

  {
    const uint4* gw = (const uint4*)wT;
    #pragma unroll
    for(int i=0;i<8;i++){
      int G = i*256 + t;             // 2048 granules of 16B
      int byte = G*16;
      *(uint4*)(sW + SWZ(byte)) = gw[G];
    }
  }
  if(sums && t<128){
    float sv  = sums[t];
    float sv2 = sums[128+t];
    float inv = 1.f/(float)NN;
    float mu = sv*inv;
    float var = sv2*inv - mu*mu;
    float sc = g[t]*rsqrtf(var + 1e-5f);
    sss[t] = sc;
    sss[128+t] = fmaf(-sc, mu, be[t]);
  }

  int w = t>>6, l = t&63, lr = l&15, lk = l>>4;
  int row = t>>2, ch = t&3;

  #pragma unroll 1
  for(int sub=0; sub<4; sub++){
    int rb = rb0 + sub*64;
    __syncthreads();   // sW/sss ready (sub=0); sA consumed by previous tile (sub>0)
    {
      int gr = rb+row; if(gr >= NN) gr = NN-1;
      if(in32){
        const float4* src = (const float4*)(in32 + (size_t)gr*D + ch*32);
        #pragma unroll
        for(int i=0;i<4;i++){
          float4 a = src[2*i], b = src[2*i+1];
          uint4 v;
          v.x = pk2(a.x, a.y);
          v.y = pk2(a.z, a.w);
          v.z = pk2(b.x, b.y);
          v.w = pk2(b.z, b.w);
          int byte = row*256 + ch*64 + i*16;
          *(uint4*)(sA + SWZ(byte)) = v;
        }
      } else {
        const uint4* src = (const uint4*)(in + (size_t)gr*D + ch*32);
        #pragma unroll
        for(int i=0;i<4;i++){
          uint4 v = src[i];
          if(sums){
            int d = ch*32 + i*8;
            unsigned int* pv = (unsigned int*)&v;
            #pragma unroll
            for(int j=0;j<4;j++){
              unsigned int u = pv[j];
              int dd = d + j*2;
              float lo = bf2f(u & 0xFFFFu);
              float hi = __uint_as_float(u & 0xFFFF0000u);
              lo = fmaxf(fmaf(sss[dd],   lo, sss[128+dd]),   0.f);
              hi = fmaxf(fmaf(sss[dd+1], hi, sss[128+dd+1]), 0.f);
              pv[j] = pk2(lo, hi);
            }
          }
          int byte = row*256 + ch*64 + i*16;
          *(uint4*)(sA + SWZ(byte)) = v;
        }
      }
    }
    __syncthreads();
    f32x4 acc[8] = {};
    #pragma unroll
    for(int kk=0; kk<4; kk++){
      int abyte = (16*w + lr)*256 + kk*64 + lk*16;
      short8 a = *(const short8*)(sA + SWZ(abyte));
      #pragma unroll
      for(int n=0;n<8;n++){
        int bbyte = (16*n + lr)*256 + kk*64 + lk*16;
        short8 b = *(const short8*)(sW + SWZ(bbyte));
        acc[n] = __builtin_amdgcn_mfma_f32_16x16x32_bf16(b, a, acc[n], 0, 0, 0);
      }
    }
    // transposed epilogue: lane (lr,lk) holds channels 16n+lk*4 of node rb+16w+lr
    {
      int gr = rb + 16*w + lr;
      if(gr < NN){
        float dv = dinv ? dinv[gr] : 1.f;
        #pragma unroll
        for(int n=0;n<8;n++){
          int chn = 16*n + lk*4;
          float b0=0.f,b1=0.f,b2=0.f,b3=0.f;
          if(bias){
            float4 bb = *(const float4*)(bias+chn);
            b0=bb.x; b1=bb.y; b2=bb.z; b3=bb.w;
          }
          float v0 = fmaf(acc[n][0], dv, b0);
          float v1 = fmaf(acc[n][1], dv, b1);
          float v2 = fmaf(acc[n][2], dv, b2);
          float v3 = fmaf(acc[n][3], dv, b3);
          uint2 o; o.x = pk2(v0,v1); o.y = pk2(v2,v3);
          *(uint2*)(outp + (size_t)gr*D + chn) = o;
        }
      }
    }
  }
}

// ---------- gather: out[v] = bf16(dinv[v] * (U[v] + sum_in U[src])) ----------
// round-3 proven structure: wave per node, lane = channel-pair, rolled loop.
__global__ __launch_bounds__(256) void k_gather16(const unsigned short* __restrict__ U,
    const int* __restrict__ rowptr, const int* __restrict__ csr_src,
    const float* __restrict__ dinv, unsigned short* __restrict__ outp){
  int node = blockIdx.x*4 + (threadIdx.x>>6);   // grid exact: 12500*4 = NN
  int l = threadIdx.x&63;
  const unsigned* U32 = (const unsigned*)U;
  unsigned u = U32[(size_t)node*64 + l];
  float a0 = bf2f(u & 0xFFFFu);
  float a1 = __uint_as_float(u & 0xFFFF0000u);
  int s = rowptr[node], e = rowptr[node+1];
  for(int base=s; base<e; base+=64){
    int idx = (base+l < e) ? csr_src[base+l] : 0;
    int n = min(64, e-base);
    for(int k=0;k<n;k++){
      int src = __shfl(idx, k, 64);
      unsigned v = U32[(size_t)src*64 + l];
      a0 += bf2f(v & 0xFFFFu);
      a1 += __uint_as_float(v & 0xFFFF0000u);
    }
  }
  float dv = dinv[node];
  ((unsigned*)outp)[(size_t)node*64 + l] = pk2(a0*dv, a1*dv);
}

// ---------- BN stats (bf16 input) -> per-layer sums buffer ----------
__global__ __launch_bounds__(256) void k_bnstats16(const unsigned short* __restrict__ x,
    float* __restrict__ sums){
  __shared__ float l1[256], l2[256];
  int b = blockIdx.x, t = threadIdx.x;
  int ch = t&127, half = t>>7;
  int rend = min((b+1)*196, NN);
  float s=0.f, s2=0.f;
  for(int r = b*196+half; r < rend; r += 2){
    float v = bf2f(x[(size_t)r*D + ch]);
    s += v; s2 = fmaf(v,v,s2);
  }
  l1[t]=s; l2[t]=s2; __syncthreads();
  if(t<128){
    s = l1[t]+l1[t+128]; s2 = l2[t]+l2[t+128];
    atomicAdd(&sums[ch], s);
    atomicAdd(&sums[128+ch], s2);
  }
}

// ---------- edge head over dst-CSR-ordered edges ----------
// 512 threads / 128 edges; A-fragments (z1) built in-register from direct
// per-lane P/Q chunk loads -> no sZ1 LDS, one barrier, LDS ~16.5KB.
__global__ __launch_bounds__(512) void k_edge(const int* __restrict__ csr_src,
    const int2* __restrict__ csr_de,
    const unsigned short* __restrict__ P16, const unsigned short* __restrict__ Q16,
    const unsigned short* __restrict__ wc2t, const float* __restrict__ bc2,
    const float* __restrict__ wc3, const float* __restrict__ bc3,
    float* __restrict__ out){
  __shared__ char sW[64*256];     // Wc2^T bf16 [64 cols][128 k], swizzled (16KB)
  __shared__ float sWc3[128];
  int t = threadIdx.x;
  int base = blockIdx.x*128;
  if(t<128) sWc3[t] = wc3[t];
  {
    const uint4* gw = (const uint4*)wc2t;
    #pragma unroll
    for(int i=0;i<2;i++){
      int G = t*2+i;                    // 512*2 = 1024 granules of 16B
      int byte = G*16;
      *(uint4*)(sW + SWZ(byte)) = gw[G];
    }
  }
  int w = t>>6, l = t&63;
  int lr = l&15, lk = l>>4;
  // per-lane A-fragment build: edge = base+16w+lr, chunk (kk,lk) = 16B
  int e = base + 16*w + lr;
  int srcv = csr_src[e];
  int dstv = csr_de[e].x;
  const uint4* prow = (const uint4*)(P16 + (size_t)srcv*D);
  const uint4* qrow = (const uint4*)(Q16 + (size_t)dstv*D);
  uint4 pv[4], qv[4];
  #pragma unroll
  for(int kk=0;kk<4;kk++){ pv[kk] = prow[kk*4 + lk]; qv[kk] = qrow[kk*4 + lk]; }
  union { short8 s; uint4 u; } af[4];
  #pragma unroll
  for(int kk=0;kk<4;kk++){
    unsigned* pp = (unsigned*)&pv[kk];
    unsigned* qq = (unsigned*)&qv[kk];
    unsigned r[4];
    #pragma unroll
    for(int j=0;j<4;j++){
      float plo = bf2f(pp[j] & 0xFFFFu);
      float phi = __uint_as_float(pp[j] & 0xFFFF0000u);
      float qlo = bf2f(qq[j] & 0xFFFFu);
      float qhi = __uint_as_float(qq[j] & 0xFFFF0000u);
      r[j] = pk2(fmaxf(plo+qlo, 0.f), fmaxf(phi+qhi, 0.f));
    }
    af[kk].u = make_uint4(r[0], r[1], r[2], r[3]);
  }
  __syncthreads();
  f32x4 acc[4] = {{0.f,0.f,0.f,0.f},{0.f,0.f,0.f,0.f},{0.f,0.f,0.f,0.f},{0.f,0.f,0.f,0.f}};
  #pragma unroll
  for(int kk=0; kk<4; kk++){
    #pragma unroll
    for(int n=0;n<4;n++){
      int bbyte = (16*n + lr)*256 + kk*64 + lk*16;
      short8 bf = *(const short8*)(sW + SWZ(bbyte));
      acc[n] = __builtin_amdgcn_mfma_f32_16x16x32_bf16(af[kk].s, bf, acc[n], 0, 0, 0);
    }
  }
  float w30[4], w31[4], bb2[4];
  #pragma unroll
  for(int n=0;n<4;n++){
    int col = 16*n + lr;
    w30[n] = sWc3[col*2+0];
    w31[n] = sWc3[col*2+1];
    bb2[n] = bc2[col];
  }
  float c30 = bc3[0], c31 = bc3[1];
  #pragma unroll
  for(int reg=0; reg<4; reg++){
    float s0=0.f, s1=0.f;
    #pragma unroll
    for(int n=0;n<4;n++){
      float z = fmaxf(acc[n][reg] + bb2[n], 0.f);
      s0 = fmaf(z, w30[n], s0);
      s1 = fmaf(z, w31[n], s1);
    }
    #pragma unroll
    for(int off=1; off<16; off<<=1){
      s0 += __shfl_xor(s0, off, 64);
      s1 += __shfl_xor(s1, off, 64);
    }
    if(lr==0){
      int eid = csr_de[base + 16*w + lk*4 + reg].y;
      float2 res; res.x = s0 + c30; res.y = s1 + c31;
      *(float2*)(out + (size_t)eid*2) = res;
    }
  }
}

extern "C" void kernel_launch(void* const* d_in, const int* in_sizes, int n_in,
                              void* d_out, int out_size, void* d_ws, size_t ws_size,
                              hipStream_t stream) {
  const float* x   = (const float*)d_in[0];
  const int* ei    = (const int*)d_in[1];
  const int* src0  = ei;
  const int* dst0  = ei + NE;
  const float* W1  = (const float*)d_in[2];
  const float* W2  = (const float*)d_in[4];
  const float* W3  = (const float*)d_in[6];
  const float* g1  = (const float*)d_in[8];
  const float* be1 = (const float*)d_in[9];
  const float* g2  = (const float*)d_in[10];
  const float* be2 = (const float*)d_in[11];
  const float* g3  = (const float*)d_in[12];
  const float* be3 = (const float*)d_in[13];
  const float* Wc1 = (const float*)d_in[14];
  const float* bc1 = (const float*)d_in[15];
  const float* Wc2 = (const float*)d_in[16];
  const float* bc2 = (const float*)d_in[17];
  const float* Wc3 = (const float*)d_in[18];
  const float* bc3 = (const float*)d_in[19];
  float* out = (float*)d_out;

  char* ws = (char*)d_ws;
  size_t off = 0;
  auto alloc = [&](size_t bytes) -> void* {
    void* p = ws + off;
    off += (bytes + 511) & ~(size_t)511;
    return p;
  };
  // cnt (padded 200704) + sums1..3 (3x1024B) covered by one memset
  int*   cnt     = (int*)alloc(NN*sizeof(int));          // 200704 padded
  float* sums1   = (float*)alloc(256*sizeof(float));
  float* sums2   = (float*)alloc(256*sizeof(float));
  float* sums3   = (float*)alloc(256*sizeof(float));
  int*   rowptr  = (int*)alloc((NN+1)*sizeof(int));
  int*   bsum    = (int*)alloc(256*sizeof(int));
  int*   csr_src = (int*)alloc(NE*sizeof(int));
  int2*  csr_de  = (int2*)alloc(NE*sizeof(int2));
  float* dinv    = (float*)alloc(NN*sizeof(float));
  unsigned short* U16 = (unsigned short*)alloc((size_t)NN*D*2);  // also P
  unsigned short* H16 = (unsigned short*)alloc((size_t)NN*D*2);
  unsigned short* Q16 = (unsigned short*)alloc((size_t)NN*D*2);
  unsigned short* w1T  = (unsigned short*)alloc(128*128*2);
  unsigned short* w2T  = (unsigned short*)alloc(128*128*2);
  unsigned short* w3T  = (unsigned short*)alloc(128*128*2);
  unsigned short* wc1aT= (unsigned short*)alloc(128*128*2);
  unsigned short* wc1bT= (unsigned short*)alloc(128*128*2);
  unsigned short* wc2T = (unsigned short*)alloc(64*128*2);

  // one memset covers cnt (200704) + sums1..3 (3072)
  hipMemsetAsync(cnt, 0, 200704 + 3*1024, stream);
  k_hist<<<(NE/4 + 255)/256, 256, 0, stream>>>(dst0, cnt);
  k_scanA<<<NBLK, 256, 0, stream>>>(cnt, bsum);
  k_scanC<<<NBLK, 256, 0, stream>>>(cnt, bsum, rowptr, dinv, cnt);
  k_fill<<<NE/256, 256, 0, stream>>>(src0, dst0, rowptr, cnt, csr_src, csr_de);
  k_prep_all<<<352, 256, 0, stream>>>(W1, W2, W3, Wc1, Wc2, w1T, w2T, w3T, wc1aT, wc1bT, wc2T);

  const int GB = NN/4;   // 12500

  // layer 1 (fp32 input converted in-kernel, no BN on input)
  k_mm<<<MMB2, 256, 0, stream>>>(nullptr, x, w1T, w1T, U16, U16,
                                 nullptr, nullptr, nullptr, dinv, nullptr, MMB2);
  k_gather16<<<GB, 256, 0, stream>>>(U16, rowptr, csr_src, dinv, H16);
  k_bnstats16<<<256, 256, 0, stream>>>(H16, sums1);
  // layer 2 (BN1 derived in-block from sums1)
  k_mm<<<MMB2, 256, 0, stream>>>(H16, nullptr, w2T, w2T, U16, U16,
                                 sums1, g1, be1, dinv, nullptr, MMB2);
  k_gather16<<<GB, 256, 0, stream>>>(U16, rowptr, csr_src, dinv, H16);
  k_bnstats16<<<256, 256, 0, stream>>>(H16, sums2);
  // layer 3
  k_mm<<<MMB2, 256, 0, stream>>>(H16, nullptr, w3T, w3T, U16, U16,
                                 sums2, g2, be2, dinv, nullptr, MMB2);
  k_gather16<<<GB, 256, 0, stream>>>(U16, rowptr, csr_src, dinv, H16);
  k_bnstats16<<<256, 256, 0, stream>>>(H16, sums3);

  // head projections (dual): P = bnrelu(H)@Wc1_top + bc1 ; Q = bnrelu(H)@Wc1_bot
  k_mm<<<2*MMB2, 256, 0, stream>>>(H16, nullptr, wc1aT, wc1bT, U16, Q16,
                                   sums3, g3, be3, nullptr, bc1, MMB2);

  // edge MLP over CSR-ordered edges
  k_edge<<<NE/128, 512, 0, stream>>>(csr_src, csr_de, U16, Q16, wc2T,
                                     bc2, Wc3, bc3, out);
}

// Round 15
// 429.401 us; speedup vs baseline: 1.1319x; 1.1319x over previous
//
#include <hip/hip_runtime.h>

#define NN 50000
#define NE 800000
#define D 128
#define MMB 782   // ceil(NN/64)
#define NBLK 196  // ceil(NN/256)

typedef __attribute__((ext_vector_type(8))) short short8;
typedef __attribute__((ext_vector_type(4))) float f32x4;

#define SWZ(b) ((b) ^ ((((b)>>8)&7)<<4))

__device__ __forceinline__ unsigned int f2bf(float f){
  unsigned int u = __float_as_uint(f);
  return (u + 0x7FFFu + ((u>>16)&1u)) >> 16;   // RNE fp32 -> bf16
}
__device__ __forceinline__ float bf2f(unsigned int u){
  return __uint_as_float(u<<16);
}
__device__ __forceinline__ unsigned int pk2(float lo, float hi){
  unsigned int r;
  asm("v_cvt_pk_bf16_f32 %0, %1, %2" : "=v"(r) : "v"(lo), "v"(hi));
  return r;
}

// ---------- CSR build ----------
__global__ void k_hist(const int* __restrict__ dst0, int* __restrict__ cnt){
  int id = blockIdx.x*256 + threadIdx.x;
  if(id < NE/4){
    int4 d = ((const int4*)dst0)[id];
    atomicAdd(&cnt[d.x],1); atomicAdd(&cnt[d.y],1);
    atomicAdd(&cnt[d.z],1); atomicAdd(&cnt[d.w],1);
  }
}

__global__ __launch_bounds__(256) void k_scanA(const int* __restrict__ cnt, int* __restrict__ bsum){
  __shared__ int sh[256];
  int b = blockIdx.x, t = threadIdx.x;
  int i = b*256 + t;
  int v = (i<NN) ? cnt[i] : 0;
  sh[t] = v; __syncthreads();
  for(int off=128; off>0; off>>=1){
    if(t<off) sh[t] += sh[t+off];
    __syncthreads();
  }
  if(t==0) bsum[b] = sh[0];
}

// folded scanB+scanC: each block redundantly scans the 196 block sums,
// then local exclusive scan -> rowptr; also dinv and cnt reset
__global__ __launch_bounds__(256) void k_scanC(const int* __restrict__ cnt, const int* __restrict__ bsum,
    int* __restrict__ rowptr, float* __restrict__ dinv, int* __restrict__ cntz){
  __shared__ int sh2[256];
  __shared__ int sh[256];
  int b = blockIdx.x, t = threadIdx.x;
  int v2 = (t<NBLK) ? bsum[t] : 0;
  sh2[t] = v2; __syncthreads();
  for(int off=1; off<256; off<<=1){
    int add = (t>=off) ? sh2[t-off] : 0;
    __syncthreads();
    sh2[t] += add;
    __syncthreads();
  }
  int base = (b>0) ? sh2[b-1] : 0;
  int i = b*256 + t;
  int v = (i<NN) ? cnt[i] : 0;
  sh[t] = v; __syncthreads();
  for(int off=1; off<256; off<<=1){
    int add = (t>=off) ? sh[t-off] : 0;
    __syncthreads();
    sh[t] += add;
    __syncthreads();
  }
  int excl = sh[t] - v;
  if(i<NN){
    rowptr[i] = base + excl;
    dinv[i] = rsqrtf((float)(v+1));
    cntz[i] = 0;
  }
  if(b==gridDim.x-1 && t==255) rowptr[NN] = NE;
}

__global__ void k_fill(const int* __restrict__ src0, const int* __restrict__ dst0,
                       const int* __restrict__ rowptr, int* __restrict__ cur,
                       int* __restrict__ csr_src, int2* __restrict__ csr_de){
  int e = blockIdx.x*256 + threadIdx.x;
  if(e<NE){
    int d = dst0[e];
    int pos = atomicAdd(&cur[d],1);
    int slot = rowptr[d]+pos;
    csr_src[slot] = src0[e];
    csr_de[slot] = make_int2(d, e);
  }
}

// all weight transposes+bf16 in one kernel
__global__ void k_prep_all(const float* __restrict__ W1, const float* __restrict__ W2,
    const float* __restrict__ W3, const float* __restrict__ Wc1, const float* __restrict__ Wc2,
    unsigned short* __restrict__ w1T, unsigned short* __restrict__ w2T,
    unsigned short* __restrict__ w3T, unsigned short* __restrict__ wc1aT,
    unsigned short* __restrict__ wc1bT, unsigned short* __restrict__ wc2T){
  int id = blockIdx.x*256 + threadIdx.x;
  if(id < 81920){
    int seg = id >> 14, q = id & 16383;
    int c = q>>7, k = q&127;
    const float* W; unsigned short* wT;
    switch(seg){
      case 0: W=W1; wT=w1T; break;
      case 1: W=W2; wT=w2T; break;
      case 2: W=W3; wT=w3T; break;
      case 3: W=Wc1; wT=wc1aT; break;
      default: W=Wc1+128*128; wT=wc1bT; break;
    }
    wT[q] = (unsigned short)f2bf(W[(size_t)k*128+c]);
  } else if(id < 90112){
    int q = id - 81920;
    int c = q>>7, k = q&127;
    wc2T[q] = (unsigned short)f2bf(Wc2[(size_t)k*64+c]);
  }
}

// ---------- node GEMM (bf16 MFMA): out = [bnrelu](in) @ W [*dinv] [+bias] ----------
// BN scale/shift derived in-block from 64-slice partials (gpart) when non-null.
// Dual mode: grid = 2*halfGrid -> second half uses wTb/outb, no bias.
// W staged in LDS (one-time 32KB coalesced copy, swizzled); operand-swapped
// MFMA -> transposed C, direct 8B stores. (round-13 verified structure)
__global__ __launch_bounds__(256) void k_mm(const unsigned short* __restrict__ in,
    const float* __restrict__ in32,
    const unsigned short* __restrict__ wTa, const unsigned short* __restrict__ wTb,
    unsigned short* __restrict__ outa, unsigned short* __restrict__ outb,
    const float* __restrict__ gpart, const float* __restrict__ g, const float* __restrict__ be,
    const float* __restrict__ dinv, const float* __restrict__ biasA, int halfGrid){
  __shared__ char sA[64*256];    // bf16 [64 rows][128], XOR-swizzled (16KB)
  __shared__ char sW[128*256];   // bf16 [128 cols][128 k], XOR-swizzled (32KB)
  __shared__ float sss[256];
  int t = threadIdx.x;
  int bid = blockIdx.x;
  bool second = bid >= halfGrid;
  int rb = (second ? bid-halfGrid : bid)*64;
  const unsigned short* wT = second ? wTb : wTa;
  unsigned short* outp = second ? outb : outa;
  const float* bias = second ? nullptr : biasA;

  {
    const uint4* gw = (const uint4*)wT;
    #pragma unroll
    for(int i=0;i<8;i++){
      int G = i*256 + t;             // 2048 granules of 16B
      int byte = G*16;
      *(uint4*)(sW + SWZ(byte)) = gw[G];
    }
  }
  if(gpart){
    if(t<128){
      float s=0.f, s2=0.f;
      #pragma unroll 4
      for(int j=0;j<64;j++){ s += gpart[j*256+t]; s2 += gpart[j*256+128+t]; }
      float inv = 1.f/(float)NN;
      float mu = s*inv;
      float var = s2*inv - mu*mu;
      float sc = g[t]*rsqrtf(var + 1e-5f);
      sss[t] = sc;
      sss[128+t] = fmaf(-sc, mu, be[t]);
    }
    __syncthreads();
  }
  {
    int row = t>>2, ch = t&3;
    int gr = rb+row; if(gr >= NN) gr = NN-1;
    if(in32){
      const float4* src = (const float4*)(in32 + (size_t)gr*D + ch*32);
      #pragma unroll
      for(int i=0;i<4;i++){
        float4 a = src[2*i], b = src[2*i+1];
        uint4 v;
        v.x = pk2(a.x, a.y);
        v.y = pk2(a.z, a.w);
        v.z = pk2(b.x, b.y);
        v.w = pk2(b.z, b.w);
        int byte = row*256 + ch*64 + i*16;
        *(uint4*)(sA + SWZ(byte)) = v;
      }
    } else {
      const uint4* src = (const uint4*)(in + (size_t)gr*D + ch*32);
      #pragma unroll
      for(int i=0;i<4;i++){
        uint4 v = src[i];
        if(gpart){
          int d = ch*32 + i*8;
          unsigned int* pv = (unsigned int*)&v;
          #pragma unroll
          for(int j=0;j<4;j++){
            unsigned int u = pv[j];
            int dd = d + j*2;
            float lo = bf2f(u & 0xFFFFu);
            float hi = __uint_as_float(u & 0xFFFF0000u);
            lo = fmaxf(fmaf(sss[dd],   lo, sss[128+dd]),   0.f);
            hi = fmaxf(fmaf(sss[dd+1], hi, sss[128+dd+1]), 0.f);
            pv[j] = pk2(lo, hi);
          }
        }
        int byte = row*256 + ch*64 + i*16;
        *(uint4*)(sA + SWZ(byte)) = v;
      }
    }
  }
  __syncthreads();
  int w = t>>6, l = t&63, lr = l&15, lk = l>>4;
  f32x4 acc[8] = {};
  #pragma unroll
  for(int kk=0; kk<4; kk++){
    int abyte = (16*w + lr)*256 + kk*64 + lk*16;
    short8 a = *(const short8*)(sA + SWZ(abyte));
    #pragma unroll
    for(int n=0;n<8;n++){
      int bbyte = (16*n + lr)*256 + kk*64 + lk*16;
      short8 b = *(const short8*)(sW + SWZ(bbyte));
      acc[n] = __builtin_amdgcn_mfma_f32_16x16x32_bf16(b, a, acc[n], 0, 0, 0);
    }
  }
  // transposed epilogue: lane (lr,lk) holds channels 16n+lk*4 of node rb+16w+lr
  {
    int gr = rb + 16*w + lr;
    if(gr < NN){
      float dv = dinv ? dinv[gr] : 1.f;
      #pragma unroll
      for(int n=0;n<8;n++){
        int chn = 16*n + lk*4;
        float b0=0.f,b1=0.f,b2=0.f,b3=0.f;
        if(bias){
          float4 bb = *(const float4*)(bias+chn);
          b0=bb.x; b1=bb.y; b2=bb.z; b3=bb.w;
        }
        float v0 = fmaf(acc[n][0], dv, b0);
        float v1 = fmaf(acc[n][1], dv, b1);
        float v2 = fmaf(acc[n][2], dv, b2);
        float v3 = fmaf(acc[n][3], dv, b3);
        uint2 o; o.x = pk2(v0,v1); o.y = pk2(v2,v3);
        *(uint2*)(outp + (size_t)gr*D + chn) = o;
      }
    }
  }
}

// ---------- gather + fused BN stats ----------
// round-3 proven inner loop untouched; epilogue: non-atomic LDS [4][256]
// per-wave slab + cross-wave reduce -> 64-slice gpart atomics.
__global__ __launch_bounds__(256) void k_gather16(const unsigned short* __restrict__ U,
    const int* __restrict__ rowptr, const int* __restrict__ csr_src,
    const float* __restrict__ dinv, unsigned short* __restrict__ outp,
    float* __restrict__ gpart){
  __shared__ float sS[4][128], sQ[4][128];
  int t = threadIdx.x;
  int wv = t>>6, l = t&63;
  int node = blockIdx.x*4 + wv;   // grid exact: 12500*4 = NN
  const unsigned* U32 = (const unsigned*)U;
  unsigned u = U32[(size_t)node*64 + l];
  float a0 = bf2f(u & 0xFFFFu);
  float a1 = __uint_as_float(u & 0xFFFF0000u);
  int s = rowptr[node], e = rowptr[node+1];
  for(int base=s; base<e; base+=64){
    int idx = (base+l < e) ? csr_src[base+l] : 0;
    int n = min(64, e-base);
    for(int k=0;k<n;k++){
      int src = __shfl(idx, k, 64);
      unsigned v = U32[(size_t)src*64 + l];
      a0 += bf2f(v & 0xFFFFu);
      a1 += __uint_as_float(v & 0xFFFF0000u);
    }
  }
  float dv = dinv[node];
  float o0 = a0*dv, o1 = a1*dv;
  ((unsigned*)outp)[(size_t)node*64 + l] = pk2(o0, o1);
  sS[wv][2*l]   = o0;    sS[wv][2*l+1] = o1;
  sQ[wv][2*l]   = o0*o0; sQ[wv][2*l+1] = o1*o1;
  __syncthreads();
  if(t<128){
    float sv = sS[0][t]+sS[1][t]+sS[2][t]+sS[3][t];
    float qv = sQ[0][t]+sQ[1][t]+sQ[2][t]+sQ[3][t];
    float* gp = gpart + (size_t)(blockIdx.x & 63)*256;
    atomicAdd(&gp[t], sv);
    atomicAdd(&gp[128+t], qv);
  }
}

// ---------- edge head over dst-CSR-ordered edges ----------
// 512 threads / 128 edges; A-fragments built in-register from direct
// per-lane P/Q chunk loads; sW staged in LDS (16KB).
__global__ __launch_bounds__(512) void k_edge(const int* __restrict__ csr_src,
    const int2* __restrict__ csr_de,
    const unsigned short* __restrict__ P16, const unsigned short* __restrict__ Q16,
    const unsigned short* __restrict__ wc2t, const float* __restrict__ bc2,
    const float* __restrict__ wc3, const float* __restrict__ bc3,
    float* __restrict__ out){
  __shared__ char sW[64*256];     // Wc2^T bf16 [64 cols][128 k], swizzled (16KB)
  __shared__ float sWc3[128];
  int t = threadIdx.x;
  int base = blockIdx.x*128;
  if(t<128) sWc3[t] = wc3[t];
  {
    const uint4* gw = (const uint4*)wc2t;
    #pragma unroll
    for(int i=0;i<2;i++){
      int G = t*2+i;                    // 512*2 = 1024 granules of 16B
      int byte = G*16;
      *(uint4*)(sW + SWZ(byte)) = gw[G];
    }
  }
  int w = t>>6, l = t&63;
  int lr = l&15, lk = l>>4;
  // per-lane A-fragment build: edge = base+16w+lr, chunk (kk,lk) = 16B
  int e = base + 16*w + lr;
  int srcv = csr_src[e];
  int dstv = csr_de[e].x;
  const uint4* prow = (const uint4*)(P16 + (size_t)srcv*D);
  const uint4* qrow = (const uint4*)(Q16 + (size_t)dstv*D);
  uint4 pv[4], qv[4];
  #pragma unroll
  for(int kk=0;kk<4;kk++){ pv[kk] = prow[kk*4 + lk]; qv[kk] = qrow[kk*4 + lk]; }
  union { short8 s; uint4 u; } af[4];
  #pragma unroll
  for(int kk=0;kk<4;kk++){
    unsigned* pp = (unsigned*)&pv[kk];
    unsigned* qq = (unsigned*)&qv[kk];
    unsigned r[4];
    #pragma unroll
    for(int j=0;j<4;j++){
      float plo = bf2f(pp[j] & 0xFFFFu);
      float phi = __uint_as_float(pp[j] & 0xFFFF0000u);
      float qlo = bf2f(qq[j] & 0xFFFFu);
      float qhi = __uint_as_float(qq[j] & 0xFFFF0000u);
      r[j] = pk2(fmaxf(plo+qlo, 0.f), fmaxf(phi+qhi, 0.f));
    }
    af[kk].u = make_uint4(r[0], r[1], r[2], r[3]);
  }
  __syncthreads();
  f32x4 acc[4] = {{0.f,0.f,0.f,0.f},{0.f,0.f,0.f,0.f},{0.f,0.f,0.f,0.f},{0.f,0.f,0.f,0.f}};
  #pragma unroll
  for(int kk=0; kk<4; kk++){
    #pragma unroll
    for(int n=0;n<4;n++){
      int bbyte = (16*n + lr)*256 + kk*64 + lk*16;
      short8 bf = *(const short8*)(sW + SWZ(bbyte));
      acc[n] = __builtin_amdgcn_mfma_f32_16x16x32_bf16(af[kk].s, bf, acc[n], 0, 0, 0);
    }
  }
  float w30[4], w31[4], bb2[4];
  #pragma unroll
  for(int n=0;n<4;n++){
    int col = 16*n + lr;
    w30[n] = sWc3[col*2+0];
    w31[n] = sWc3[col*2+1];
    bb2[n] = bc2[col];
  }
  float c30 = bc3[0], c31 = bc3[1];
  #pragma unroll
  for(int reg=0; reg<4; reg++){
    float s0=0.f, s1=0.f;
    #pragma unroll
    for(int n=0;n<4;n++){
      float z = fmaxf(acc[n][reg] + bb2[n], 0.f);
      s0 = fmaf(z, w30[n], s0);
      s1 = fmaf(z, w31[n], s1);
    }
    #pragma unroll
    for(int off=1; off<16; off<<=1){
      s0 += __shfl_xor(s0, off, 64);
      s1 += __shfl_xor(s1, off, 64);
    }
    if(lr==0){
      int eid = csr_de[base + 16*w + lk*4 + reg].y;
      float2 res; res.x = s0 + c30; res.y = s1 + c31;
      *(float2*)(out + (size_t)eid*2) = res;
    }
  }
}

extern "C" void kernel_launch(void* const* d_in, const int* in_sizes, int n_in,
                              void* d_out, int out_size, void* d_ws, size_t ws_size,
                              hipStream_t stream) {
  const float* x   = (const float*)d_in[0];
  const int* ei    = (const int*)d_in[1];
  const int* src0  = ei;
  const int* dst0  = ei + NE;
  const float* W1  = (const float*)d_in[2];
  const float* W2  = (const float*)d_in[4];
  const float* W3  = (const float*)d_in[6];
  const float* g1  = (const float*)d_in[8];
  const float* be1 = (const float*)d_in[9];
  const float* g2  = (const float*)d_in[10];
  const float* be2 = (const float*)d_in[11];
  const float* g3  = (const float*)d_in[12];
  const float* be3 = (const float*)d_in[13];
  const float* Wc1 = (const float*)d_in[14];
  const float* bc1 = (const float*)d_in[15];
  const float* Wc2 = (const float*)d_in[16];
  const float* bc2 = (const float*)d_in[17];
  const float* Wc3 = (const float*)d_in[18];
  const float* bc3 = (const float*)d_in[19];
  float* out = (float*)d_out;

  char* ws = (char*)d_ws;
  size_t off = 0;
  auto alloc = [&](size_t bytes) -> void* {
    void* p = ws + off;
    off += (bytes + 511) & ~(size_t)511;
    return p;
  };
  // cnt (padded 200704) + gpart1..3 (3x65536) covered by one memset
  int*   cnt     = (int*)alloc(NN*sizeof(int));          // 200704 padded
  float* gpart1  = (float*)alloc(64*256*sizeof(float));  // 65536
  float* gpart2  = (float*)alloc(64*256*sizeof(float));
  float* gpart3  = (float*)alloc(64*256*sizeof(float));
  int*   rowptr  = (int*)alloc((NN+1)*sizeof(int));
  int*   bsum    = (int*)alloc(256*sizeof(int));
  int*   csr_src = (int*)alloc(NE*sizeof(int));
  int2*  csr_de  = (int2*)alloc(NE*sizeof(int2));
  float* dinv    = (float*)alloc(NN*sizeof(float));
  unsigned short* U16 = (unsigned short*)alloc((size_t)NN*D*2);  // also P
  unsigned short* H16 = (unsigned short*)alloc((size_t)NN*D*2);
  unsigned short* Q16 = (unsigned short*)alloc((size_t)NN*D*2);
  unsigned short* w1T  = (unsigned short*)alloc(128*128*2);
  unsigned short* w2T  = (unsigned short*)alloc(128*128*2);
  unsigned short* w3T  = (unsigned short*)alloc(128*128*2);
  unsigned short* wc1aT= (unsigned short*)alloc(128*128*2);
  unsigned short* wc1bT= (unsigned short*)alloc(128*128*2);
  unsigned short* wc2T = (unsigned short*)alloc(64*128*2);

  // one memset covers cnt (200704) + gpart1..3 (196608)
  hipMemsetAsync(cnt, 0, 200704 + 3*65536, stream);
  k_hist<<<(NE/4 + 255)/256, 256, 0, stream>>>(dst0, cnt);
  k_scanA<<<NBLK, 256, 0, stream>>>(cnt, bsum);
  k_scanC<<<NBLK, 256, 0, stream>>>(cnt, bsum, rowptr, dinv, cnt);
  k_fill<<<NE/256, 256, 0, stream>>>(src0, dst0, rowptr, cnt, csr_src, csr_de);
  k_prep_all<<<352, 256, 0, stream>>>(W1, W2, W3, Wc1, Wc2, w1T, w2T, w3T, wc1aT, wc1bT, wc2T);

  const int GB = NN/4;   // 12500

  // layer 1 (fp32 input converted in-kernel, no BN on input)
  k_mm<<<MMB, 256, 0, stream>>>(nullptr, x, w1T, w1T, U16, U16,
                                nullptr, nullptr, nullptr, dinv, nullptr, MMB);
  k_gather16<<<GB, 256, 0, stream>>>(U16, rowptr, csr_src, dinv, H16, gpart1);
  // layer 2 (BN1 derived in-block from gpart1)
  k_mm<<<MMB, 256, 0, stream>>>(H16, nullptr, w2T, w2T, U16, U16,
                                gpart1, g1, be1, dinv, nullptr, MMB);
  k_gather16<<<GB, 256, 0, stream>>>(U16, rowptr, csr_src, dinv, H16, gpart2);
  // layer 3
  k_mm<<<MMB, 256, 0, stream>>>(H16, nullptr, w3T, w3T, U16, U16,
                                gpart2, g2, be2, dinv, nullptr, MMB);
  k_gather16<<<GB, 256, 0, stream>>>(U16, rowptr, csr_src, dinv, H16, gpart3);

  // head projections (dual): P = bnrelu(H)@Wc1_top + bc1 ; Q = bnrelu(H)@Wc1_bot
  k_mm<<<2*MMB, 256, 0, stream>>>(H16, nullptr, wc1aT, wc1bT, U16, Q16,
                                  gpart3, g3, be3, nullptr, bc1, MMB);

  // edge MLP over CSR-ordered edges
  k_edge<<<NE/128, 512, 0, stream>>>(csr_src, csr_de, U16, Q16, wc2T,
                                     bc2, Wc3, bc3, out);
}

// Round 16
// 410.624 us; speedup vs baseline: 1.1836x; 1.0457x over previous
//
#include <hip/hip_runtime.h>

#define NN 50000
#define NE 800000
#define D 128
#define MMB 782   // ceil(NN/64)
#define NBLK 196  // ceil(NN/256)

typedef __attribute__((ext_vector_type(8))) short short8;
typedef __attribute__((ext_vector_type(4))) float f32x4;

#define SWZ(b) ((b) ^ ((((b)>>8)&7)<<4))

__device__ __forceinline__ unsigned int f2bf(float f){
  unsigned int u = __float_as_uint(f);
  return (u + 0x7FFFu + ((u>>16)&1u)) >> 16;   // RNE fp32 -> bf16
}
__device__ __forceinline__ float bf2f(unsigned int u){
  return __uint_as_float(u<<16);
}
__device__ __forceinline__ unsigned int pk2(float lo, float hi){
  unsigned int r;
  asm("v_cvt_pk_bf16_f32 %0, %1, %2" : "=v"(r) : "v"(lo), "v"(hi));
  return r;
}

// ---------- CSR build ----------
__global__ void k_hist(const int* __restrict__ dst0, int* __restrict__ cnt){
  int id = blockIdx.x*256 + threadIdx.x;
  if(id < NE/4){
    int4 d = ((const int4*)dst0)[id];
    atomicAdd(&cnt[d.x],1); atomicAdd(&cnt[d.y],1);
    atomicAdd(&cnt[d.z],1); atomicAdd(&cnt[d.w],1);
  }
}

__global__ __launch_bounds__(256) void k_scanA(const int* __restrict__ cnt, int* __restrict__ bsum){
  __shared__ int sh[256];
  int b = blockIdx.x, t = threadIdx.x;
  int i = b*256 + t;
  int v = (i<NN) ? cnt[i] : 0;
  sh[t] = v; __syncthreads();
  for(int off=128; off>0; off>>=1){
    if(t<off) sh[t] += sh[t+off];
    __syncthreads();
  }
  if(t==0) bsum[b] = sh[0];
}

// folded scanB+scanC: each block redundantly scans the 196 block sums,
// then local exclusive scan -> rowptr; also dinv and cnt reset
__global__ __launch_bounds__(256) void k_scanC(const int* __restrict__ cnt, const int* __restrict__ bsum,
    int* __restrict__ rowptr, float* __restrict__ dinv, int* __restrict__ cntz){
  __shared__ int sh2[256];
  __shared__ int sh[256];
  int b = blockIdx.x, t = threadIdx.x;
  int v2 = (t<NBLK) ? bsum[t] : 0;
  sh2[t] = v2; __syncthreads();
  for(int off=1; off<256; off<<=1){
    int add = (t>=off) ? sh2[t-off] : 0;
    __syncthreads();
    sh2[t] += add;
    __syncthreads();
  }
  int base = (b>0) ? sh2[b-1] : 0;
  int i = b*256 + t;
  int v = (i<NN) ? cnt[i] : 0;
  sh[t] = v; __syncthreads();
  for(int off=1; off<256; off<<=1){
    int add = (t>=off) ? sh[t-off] : 0;
    __syncthreads();
    sh[t] += add;
    __syncthreads();
  }
  int excl = sh[t] - v;
  if(i<NN){
    rowptr[i] = base + excl;
    dinv[i] = rsqrtf((float)(v+1));
    cntz[i] = 0;
  }
  if(b==gridDim.x-1 && t==255) rowptr[NN] = NE;
}

__global__ void k_fill(const int* __restrict__ src0, const int* __restrict__ dst0,
                       const int* __restrict__ rowptr, int* __restrict__ cur,
                       int* __restrict__ csr_src, int2* __restrict__ csr_de){
  int e = blockIdx.x*256 + threadIdx.x;
  if(e<NE){
    int d = dst0[e];
    int pos = atomicAdd(&cur[d],1);
    int slot = rowptr[d]+pos;
    csr_src[slot] = src0[e];
    csr_de[slot] = make_int2(d, e);
  }
}

// all weight transposes+bf16 in one kernel
__global__ void k_prep_all(const float* __restrict__ W1, const float* __restrict__ W2,
    const float* __restrict__ W3, const float* __restrict__ Wc1, const float* __restrict__ Wc2,
    unsigned short* __restrict__ w1T, unsigned short* __restrict__ w2T,
    unsigned short* __restrict__ w3T, unsigned short* __restrict__ wc1aT,
    unsigned short* __restrict__ wc1bT, unsigned short* __restrict__ wc2T){
  int id = blockIdx.x*256 + threadIdx.x;
  if(id < 81920){
    int seg = id >> 14, q = id & 16383;
    int c = q>>7, k = q&127;
    const float* W; unsigned short* wT;
    switch(seg){
      case 0: W=W1; wT=w1T; break;
      case 1: W=W2; wT=w2T; break;
      case 2: W=W3; wT=w3T; break;
      case 3: W=Wc1; wT=wc1aT; break;
      default: W=Wc1+128*128; wT=wc1bT; break;
    }
    wT[q] = (unsigned short)f2bf(W[(size_t)k*128+c]);
  } else if(id < 90112){
    int q = id - 81920;
    int c = q>>7, k = q&127;
    wc2T[q] = (unsigned short)f2bf(Wc2[(size_t)k*64+c]);
  }
}

// ---------- node GEMM (bf16 MFMA): out = [bnrelu](in) @ W [*dinv] [+bias] ----------
// A-fragments built IN-REGISTER from direct per-lane global loads (k_edge
// round-11 pattern; rows sequential here). sW staged in LDS (32KB). BN
// scale/shift derived from 64-slice gpart; applied in-register. Operand-
// swapped MFMA -> transposed C, direct 8B stores. One barrier total.
__global__ __launch_bounds__(256) void k_mm(const unsigned short* __restrict__ in,
    const float* __restrict__ in32,
    const unsigned short* __restrict__ wTa, const unsigned short* __restrict__ wTb,
    unsigned short* __restrict__ outa, unsigned short* __restrict__ outb,
    const float* __restrict__ gpart, const float* __restrict__ g, const float* __restrict__ be,
    const float* __restrict__ dinv, const float* __restrict__ biasA, int halfGrid){
  __shared__ char sW[128*256];   // bf16 [128 cols][128 k], XOR-swizzled (32KB)
  __shared__ float sss[256];
  int t = threadIdx.x;
  int bid = blockIdx.x;
  bool second = bid >= halfGrid;
  int rb = (second ? bid-halfGrid : bid)*64;
  const unsigned short* wT = second ? wTb : wTa;
  unsigned short* outp = second ? outb : outa;
  const float* bias = second ? nullptr : biasA;

  {
    const uint4* gw = (const uint4*)wT;
    #pragma unroll
    for(int i=0;i<8;i++){
      int G = i*256 + t;             // 2048 granules of 16B
      int byte = G*16;
      *(uint4*)(sW + SWZ(byte)) = gw[G];
    }
  }
  if(gpart && t<128){
    float s=0.f, s2=0.f;
    #pragma unroll 4
    for(int j=0;j<64;j++){ s += gpart[j*256+t]; s2 += gpart[j*256+128+t]; }
    float inv = 1.f/(float)NN;
    float mu = s*inv;
    float var = s2*inv - mu*mu;
    float sc = g[t]*rsqrtf(var + 1e-5f);
    sss[t] = sc;
    sss[128+t] = fmaf(-sc, mu, be[t]);
  }
  __syncthreads();   // sW + sss ready

  int w = t>>6, l = t&63, lr = l&15, lk = l>>4;
  int gr = rb + 16*w + lr;
  int grc = gr < NN ? gr : NN-1;
  union { short8 s; uint4 u; } af[4];
  if(in32){
    const float4* src = (const float4*)(in32 + (size_t)grc*D);
    #pragma unroll
    for(int kk=0;kk<4;kk++){
      float4 a = src[kk*8 + lk*2], b = src[kk*8 + lk*2 + 1];
      af[kk].u.x = pk2(a.x, a.y);
      af[kk].u.y = pk2(a.z, a.w);
      af[kk].u.z = pk2(b.x, b.y);
      af[kk].u.w = pk2(b.z, b.w);
    }
  } else {
    const uint4* src = (const uint4*)(in + (size_t)grc*D);
    #pragma unroll
    for(int kk=0;kk<4;kk++){
      uint4 v = src[kk*4 + lk];
      if(gpart){
        int d = kk*32 + lk*8;
        unsigned int* pv = (unsigned int*)&v;
        #pragma unroll
        for(int j=0;j<4;j++){
          unsigned int u = pv[j];
          int dd = d + j*2;
          float lo = bf2f(u & 0xFFFFu);
          float hi = __uint_as_float(u & 0xFFFF0000u);
          lo = fmaxf(fmaf(sss[dd],   lo, sss[128+dd]),   0.f);
          hi = fmaxf(fmaf(sss[dd+1], hi, sss[128+dd+1]), 0.f);
          pv[j] = pk2(lo, hi);
        }
      }
      af[kk].u = v;
    }
  }
  f32x4 acc[8] = {};
  #pragma unroll
  for(int kk=0; kk<4; kk++){
    #pragma unroll
    for(int n=0;n<8;n++){
      int bbyte = (16*n + lr)*256 + kk*64 + lk*16;
      short8 b = *(const short8*)(sW + SWZ(bbyte));
      acc[n] = __builtin_amdgcn_mfma_f32_16x16x32_bf16(b, af[kk].s, acc[n], 0, 0, 0);
    }
  }
  // transposed epilogue: lane (lr,lk) holds channels 16n+lk*4 of node gr
  if(gr < NN){
    float dv = dinv ? dinv[gr] : 1.f;
    #pragma unroll
    for(int n=0;n<8;n++){
      int chn = 16*n + lk*4;
      float b0=0.f,b1=0.f,b2=0.f,b3=0.f;
      if(bias){
        float4 bb = *(const float4*)(bias+chn);
        b0=bb.x; b1=bb.y; b2=bb.z; b3=bb.w;
      }
      float v0 = fmaf(acc[n][0], dv, b0);
      float v1 = fmaf(acc[n][1], dv, b1);
      float v2 = fmaf(acc[n][2], dv, b2);
      float v3 = fmaf(acc[n][3], dv, b3);
      uint2 o; o.x = pk2(v0,v1); o.y = pk2(v2,v3);
      *(uint2*)(outp + (size_t)gr*D + chn) = o;
    }
  }
}

// ---------- gather + fused BN stats ----------
// round-3 proven inner loop untouched; epilogue: non-atomic LDS [4][256]
// per-wave slab + cross-wave reduce -> 64-slice gpart atomics.
__global__ __launch_bounds__(256) void k_gather16(const unsigned short* __restrict__ U,
    const int* __restrict__ rowptr, const int* __restrict__ csr_src,
    const float* __restrict__ dinv, unsigned short* __restrict__ outp,
    float* __restrict__ gpart){
  __shared__ float sS[4][128], sQ[4][128];
  int t = threadIdx.x;
  int wv = t>>6, l = t&63;
  int node = blockIdx.x*4 + wv;   // grid exact: 12500*4 = NN
  const unsigned* U32 = (const unsigned*)U;
  unsigned u = U32[(size_t)node*64 + l];
  float a0 = bf2f(u & 0xFFFFu);
  float a1 = __uint_as_float(u & 0xFFFF0000u);
  int s = rowptr[node], e = rowptr[node+1];
  for(int base=s; base<e; base+=64){
    int idx = (base+l < e) ? csr_src[base+l] : 0;
    int n = min(64, e-base);
    for(int k=0;k<n;k++){
      int src = __shfl(idx, k, 64);
      unsigned v = U32[(size_t)src*64 + l];
      a0 += bf2f(v & 0xFFFFu);
      a1 += __uint_as_float(v & 0xFFFF0000u);
    }
  }
  float dv = dinv[node];
  float o0 = a0*dv, o1 = a1*dv;
  ((unsigned*)outp)[(size_t)node*64 + l] = pk2(o0, o1);
  sS[wv][2*l]   = o0;    sS[wv][2*l+1] = o1;
  sQ[wv][2*l]   = o0*o0; sQ[wv][2*l+1] = o1*o1;
  __syncthreads();
  if(t<128){
    float sv = sS[0][t]+sS[1][t]+sS[2][t]+sS[3][t];
    float qv = sQ[0][t]+sQ[1][t]+sQ[2][t]+sQ[3][t];
    float* gp = gpart + (size_t)(blockIdx.x & 63)*256;
    atomicAdd(&gp[t], sv);
    atomicAdd(&gp[128+t], qv);
  }
}

// ---------- edge head over dst-CSR-ordered edges ----------
// 512 threads / 128 edges; A-fragments built in-register from direct
// per-lane P/Q chunk loads; sW staged in LDS (16KB).
__global__ __launch_bounds__(512) void k_edge(const int* __restrict__ csr_src,
    const int2* __restrict__ csr_de,
    const unsigned short* __restrict__ P16, const unsigned short* __restrict__ Q16,
    const unsigned short* __restrict__ wc2t, const float* __restrict__ bc2,
    const float* __restrict__ wc3, const float* __restrict__ bc3,
    float* __restrict__ out){
  __shared__ char sW[64*256];     // Wc2^T bf16 [64 cols][128 k], swizzled (16KB)
  __shared__ float sWc3[128];
  int t = threadIdx.x;
  int base = blockIdx.x*128;
  if(t<128) sWc3[t] = wc3[t];
  {
    const uint4* gw = (const uint4*)wc2t;
    #pragma unroll
    for(int i=0;i<2;i++){
      int G = t*2+i;                    // 512*2 = 1024 granules of 16B
      int byte = G*16;
      *(uint4*)(sW + SWZ(byte)) = gw[G];
    }
  }
  int w = t>>6, l = t&63;
  int lr = l&15, lk = l>>4;
  // per-lane A-fragment build: edge = base+16w+lr, chunk (kk,lk) = 16B
  int e = base + 16*w + lr;
  int srcv = csr_src[e];
  int dstv = csr_de[e].x;
  const uint4* prow = (const uint4*)(P16 + (size_t)srcv*D);
  const uint4* qrow = (const uint4*)(Q16 + (size_t)dstv*D);
  uint4 pv[4], qv[4];
  #pragma unroll
  for(int kk=0;kk<4;kk++){ pv[kk] = prow[kk*4 + lk]; qv[kk] = qrow[kk*4 + lk]; }
  union { short8 s; uint4 u; } af[4];
  #pragma unroll
  for(int kk=0;kk<4;kk++){
    unsigned* pp = (unsigned*)&pv[kk];
    unsigned* qq = (unsigned*)&qv[kk];
    unsigned r[4];
    #pragma unroll
    for(int j=0;j<4;j++){
      float plo = bf2f(pp[j] & 0xFFFFu);
      float phi = __uint_as_float(pp[j] & 0xFFFF0000u);
      float qlo = bf2f(qq[j] & 0xFFFFu);
      float qhi = __uint_as_float(qq[j] & 0xFFFF0000u);
      r[j] = pk2(fmaxf(plo+qlo, 0.f), fmaxf(phi+qhi, 0.f));
    }
    af[kk].u = make_uint4(r[0], r[1], r[2], r[3]);
  }
  __syncthreads();
  f32x4 acc[4] = {{0.f,0.f,0.f,0.f},{0.f,0.f,0.f,0.f},{0.f,0.f,0.f,0.f},{0.f,0.f,0.f,0.f}};
  #pragma unroll
  for(int kk=0; kk<4; kk++){
    #pragma unroll
    for(int n=0;n<4;n++){
      int bbyte = (16*n + lr)*256 + kk*64 + lk*16;
      short8 bf = *(const short8*)(sW + SWZ(bbyte));
      acc[n] = __builtin_amdgcn_mfma_f32_16x16x32_bf16(af[kk].s, bf, acc[n], 0, 0, 0);
    }
  }
  float w30[4], w31[4], bb2[4];
  #pragma unroll
  for(int n=0;n<4;n++){
    int col = 16*n + lr;
    w30[n] = sWc3[col*2+0];
    w31[n] = sWc3[col*2+1];
    bb2[n] = bc2[col];
  }
  float c30 = bc3[0], c31 = bc3[1];
  #pragma unroll
  for(int reg=0; reg<4; reg++){
    float s0=0.f, s1=0.f;
    #pragma unroll
    for(int n=0;n<4;n++){
      float z = fmaxf(acc[n][reg] + bb2[n], 0.f);
      s0 = fmaf(z, w30[n], s0);
      s1 = fmaf(z, w31[n], s1);
    }
    #pragma unroll
    for(int off=1; off<16; off<<=1){
      s0 += __shfl_xor(s0, off, 64);
      s1 += __shfl_xor(s1, off, 64);
    }
    if(lr==0){
      int eid = csr_de[base + 16*w + lk*4 + reg].y;
      float2 res; res.x = s0 + c30; res.y = s1 + c31;
      *(float2*)(out + (size_t)eid*2) = res;
    }
  }
}

extern "C" void kernel_launch(void* const* d_in, const int* in_sizes, int n_in,
                              void* d_out, int out_size, void* d_ws, size_t ws_size,
                              hipStream_t stream) {
  const float* x   = (const float*)d_in[0];
  const int* ei    = (const int*)d_in[1];
  const int* src0  = ei;
  const int* dst0  = ei + NE;
  const float* W1  = (const float*)d_in[2];
  const float* W2  = (const float*)d_in[4];
  const float* W3  = (const float*)d_in[6];
  const float* g1  = (const float*)d_in[8];
  const float* be1 = (const float*)d_in[9];
  const float* g2  = (const float*)d_in[10];
  const float* be2 = (const float*)d_in[11];
  const float* g3  = (const float*)d_in[12];
  const float* be3 = (const float*)d_in[13];
  const float* Wc1 = (const float*)d_in[14];
  const float* bc1 = (const float*)d_in[15];
  const float* Wc2 = (const float*)d_in[16];
  const float* bc2 = (const float*)d_in[17];
  const float* Wc3 = (const float*)d_in[18];
  const float* bc3 = (const float*)d_in[19];
  float* out = (float*)d_out;

  char* ws = (char*)d_ws;
  size_t off = 0;
  auto alloc = [&](size_t bytes) -> void* {
    void* p = ws + off;
    off += (bytes + 511) & ~(size_t)511;
    return p;
  };
  // cnt (padded 200704) + gpart1..3 (3x65536) covered by one memset
  int*   cnt     = (int*)alloc(NN*sizeof(int));          // 200704 padded
  float* gpart1  = (float*)alloc(64*256*sizeof(float));  // 65536
  float* gpart2  = (float*)alloc(64*256*sizeof(float));
  float* gpart3  = (float*)alloc(64*256*sizeof(float));
  int*   rowptr  = (int*)alloc((NN+1)*sizeof(int));
  int*   bsum    = (int*)alloc(256*sizeof(int));
  int*   csr_src = (int*)alloc(NE*sizeof(int));
  int2*  csr_de  = (int2*)alloc(NE*sizeof(int2));
  float* dinv    = (float*)alloc(NN*sizeof(float));
  unsigned short* U16 = (unsigned short*)alloc((size_t)NN*D*2);  // also P
  unsigned short* H16 = (unsigned short*)alloc((size_t)NN*D*2);
  unsigned short* Q16 = (unsigned short*)alloc((size_t)NN*D*2);
  unsigned short* w1T  = (unsigned short*)alloc(128*128*2);
  unsigned short* w2T  = (unsigned short*)alloc(128*128*2);
  unsigned short* w3T  = (unsigned short*)alloc(128*128*2);
  unsigned short* wc1aT= (unsigned short*)alloc(128*128*2);
  unsigned short* wc1bT= (unsigned short*)alloc(128*128*2);
  unsigned short* wc2T = (unsigned short*)alloc(64*128*2);

  // one memset covers cnt (200704) + gpart1..3 (196608)
  hipMemsetAsync(cnt, 0, 200704 + 3*65536, stream);
  k_hist<<<(NE/4 + 255)/256, 256, 0, stream>>>(dst0, cnt);
  k_scanA<<<NBLK, 256, 0, stream>>>(cnt, bsum);
  k_scanC<<<NBLK, 256, 0, stream>>>(cnt, bsum, rowptr, dinv, cnt);
  k_fill<<<NE/256, 256, 0, stream>>>(src0, dst0, rowptr, cnt, csr_src, csr_de);
  k_prep_all<<<352, 256, 0, stream>>>(W1, W2, W3, Wc1, Wc2, w1T, w2T, w3T, wc1aT, wc1bT, wc2T);

  const int GB = NN/4;   // 12500

  // layer 1 (fp32 input converted in-kernel, no BN on input)
  k_mm<<<MMB, 256, 0, stream>>>(nullptr, x, w1T, w1T, U16, U16,
                                nullptr, nullptr, nullptr, dinv, nullptr, MMB);
  k_gather16<<<GB, 256, 0, stream>>>(U16, rowptr, csr_src, dinv, H16, gpart1);
  // layer 2 (BN1 derived in-block from gpart1)
  k_mm<<<MMB, 256, 0, stream>>>(H16, nullptr, w2T, w2T, U16, U16,
                                gpart1, g1, be1, dinv, nullptr, MMB);
  k_gather16<<<GB, 256, 0, stream>>>(U16, rowptr, csr_src, dinv, H16, gpart2);
  // layer 3
  k_mm<<<MMB, 256, 0, stream>>>(H16, nullptr, w3T, w3T, U16, U16,
                                gpart2, g2, be2, dinv, nullptr, MMB);
  k_gather16<<<GB, 256, 0, stream>>>(U16, rowptr, csr_src, dinv, H16, gpart3);

  // head projections (dual): P = bnrelu(H)@Wc1_top + bc1 ; Q = bnrelu(H)@Wc1_bot
  k_mm<<<2*MMB, 256, 0, stream>>>(H16, nullptr, wc1aT, wc1bT, U16, Q16,
                                  gpart3, g3, be3, nullptr, bc1, MMB);

  // edge MLP over CSR-ordered edges
  k_edge<<<NE/128, 512, 0, stream>>>(csr_src, csr_de, U16, Q16, wc2T,
                                     bc2, Wc3, bc3, out);
}

// Round 17
// 401.308 us; speedup vs baseline: 1.2111x; 1.0232x over previous
//
#include <hip/hip_runtime.h>

#define NN 50000
#define NE 800000
#define D 128
#define MMB 782   // ceil(NN/64)
#define NBLK 196  // ceil(NN/256)
#define FB 3125   // NE/256 fill blocks

typedef __attribute__((ext_vector_type(8))) short short8;
typedef __attribute__((ext_vector_type(4))) float f32x4;

#define SWZ(b) ((b) ^ ((((b)>>8)&7)<<4))

__device__ __forceinline__ unsigned int f2bf(float f){
  unsigned int u = __float_as_uint(f);
  return (u + 0x7FFFu + ((u>>16)&1u)) >> 16;   // RNE fp32 -> bf16
}
__device__ __forceinline__ float bf2f(unsigned int u){
  return __uint_as_float(u<<16);
}
__device__ __forceinline__ unsigned int pk2(float lo, float hi){
  unsigned int r;
  asm("v_cvt_pk_bf16_f32 %0, %1, %2" : "=v"(r) : "v"(lo), "v"(hi));
  return r;
}

// ---------- fused hist + weight-prep ----------
__global__ void k_histprep(const int* __restrict__ dst0, int* __restrict__ cnt,
    const float* __restrict__ W1, const float* __restrict__ W2,
    const float* __restrict__ W3, const float* __restrict__ Wc1, const float* __restrict__ Wc2,
    unsigned short* __restrict__ w1T, unsigned short* __restrict__ w2T,
    unsigned short* __restrict__ w3T, unsigned short* __restrict__ wc1aT,
    unsigned short* __restrict__ wc1bT, unsigned short* __restrict__ wc2T){
  int id = blockIdx.x*256 + threadIdx.x;
  if(id < NE/4){
    int4 d = ((const int4*)dst0)[id];
    atomicAdd(&cnt[d.x],1); atomicAdd(&cnt[d.y],1);
    atomicAdd(&cnt[d.z],1); atomicAdd(&cnt[d.w],1);
  }
  if(id < 81920){
    int seg = id >> 14, q = id & 16383;
    int c = q>>7, k = q&127;
    const float* W; unsigned short* wT;
    switch(seg){
      case 0: W=W1; wT=w1T; break;
      case 1: W=W2; wT=w2T; break;
      case 2: W=W3; wT=w3T; break;
      case 3: W=Wc1; wT=wc1aT; break;
      default: W=Wc1+128*128; wT=wc1bT; break;
    }
    wT[q] = (unsigned short)f2bf(W[(size_t)k*128+c]);
  } else if(id < 90112){
    int q = id - 81920;
    int c = q>>7, k = q&127;
    wc2T[q] = (unsigned short)f2bf(Wc2[(size_t)k*64+c]);
  }
}

__global__ __launch_bounds__(256) void k_scanA(const int* __restrict__ cnt, int* __restrict__ bsum){
  __shared__ int sh[256];
  int b = blockIdx.x, t = threadIdx.x;
  int i = b*256 + t;
  int v = (i<NN) ? cnt[i] : 0;
  sh[t] = v; __syncthreads();
  for(int off=128; off>0; off>>=1){
    if(t<off) sh[t] += sh[t+off];
    __syncthreads();
  }
  if(t==0) bsum[b] = sh[0];
}

// folded scanB+scanC: each block redundantly scans the 196 block sums,
// then local exclusive scan -> rowptr; also dinv and cnt reset
__global__ __launch_bounds__(256) void k_scanC(const int* __restrict__ cnt, const int* __restrict__ bsum,
    int* __restrict__ rowptr, float* __restrict__ dinv, int* __restrict__ cntz){
  __shared__ int sh2[256];
  __shared__ int sh[256];
  int b = blockIdx.x, t = threadIdx.x;
  int v2 = (t<NBLK) ? bsum[t] : 0;
  sh2[t] = v2; __syncthreads();
  for(int off=1; off<256; off<<=1){
    int add = (t>=off) ? sh2[t-off] : 0;
    __syncthreads();
    sh2[t] += add;
    __syncthreads();
  }
  int base = (b>0) ? sh2[b-1] : 0;
  int i = b*256 + t;
  int v = (i<NN) ? cnt[i] : 0;
  sh[t] = v; __syncthreads();
  for(int off=1; off<256; off<<=1){
    int add = (t>=off) ? sh[t-off] : 0;
    __syncthreads();
    sh[t] += add;
    __syncthreads();
  }
  int excl = sh[t] - v;
  if(i<NN){
    rowptr[i] = base + excl;
    dinv[i] = rsqrtf((float)(v+1));
    cntz[i] = 0;
  }
  if(b==gridDim.x-1 && t==255) rowptr[NN] = NE;
}

// ---------- node GEMM body (shared by k_mm and k_fillmm) ----------
// A-fragments in-register from per-lane global loads; sW staged in LDS;
// operand-swapped MFMA -> transposed C, direct 8B stores.
__device__ __forceinline__ void mm_body(int rb,
    const unsigned short* __restrict__ in, const float* __restrict__ in32,
    const unsigned short* __restrict__ wT, unsigned short* __restrict__ outp,
    const float* __restrict__ gpart, const float* __restrict__ g, const float* __restrict__ be,
    const float* __restrict__ dinv, const float* __restrict__ bias){
  __shared__ char sW[128*256];   // bf16 [128 cols][128 k], XOR-swizzled (32KB)
  __shared__ float sss[256];
  int t = threadIdx.x;
  {
    const uint4* gw = (const uint4*)wT;
    #pragma unroll
    for(int i=0;i<8;i++){
      int G = i*256 + t;             // 2048 granules of 16B
      int byte = G*16;
      *(uint4*)(sW + SWZ(byte)) = gw[G];
    }
  }
  if(gpart && t<128){
    float s=0.f, s2=0.f;
    #pragma unroll 4
    for(int j=0;j<64;j++){ s += gpart[j*256+t]; s2 += gpart[j*256+128+t]; }
    float inv = 1.f/(float)NN;
    float mu = s*inv;
    float var = s2*inv - mu*mu;
    float sc = g[t]*rsqrtf(var + 1e-5f);
    sss[t] = sc;
    sss[128+t] = fmaf(-sc, mu, be[t]);
  }
  __syncthreads();   // sW + sss ready

  int w = t>>6, l = t&63, lr = l&15, lk = l>>4;
  int gr = rb + 16*w + lr;
  int grc = gr < NN ? gr : NN-1;
  union { short8 s; uint4 u; } af[4];
  if(in32){
    const float4* src = (const float4*)(in32 + (size_t)grc*D);
    #pragma unroll
    for(int kk=0;kk<4;kk++){
      float4 a = src[kk*8 + lk*2], b = src[kk*8 + lk*2 + 1];
      af[kk].u.x = pk2(a.x, a.y);
      af[kk].u.y = pk2(a.z, a.w);
      af[kk].u.z = pk2(b.x, b.y);
      af[kk].u.w = pk2(b.z, b.w);
    }
  } else {
    const uint4* src = (const uint4*)(in + (size_t)grc*D);
    #pragma unroll
    for(int kk=0;kk<4;kk++){
      uint4 v = src[kk*4 + lk];
      if(gpart){
        int d = kk*32 + lk*8;
        unsigned int* pv = (unsigned int*)&v;
        #pragma unroll
        for(int j=0;j<4;j++){
          unsigned int u = pv[j];
          int dd = d + j*2;
          float lo = bf2f(u & 0xFFFFu);
          float hi = __uint_as_float(u & 0xFFFF0000u);
          lo = fmaxf(fmaf(sss[dd],   lo, sss[128+dd]),   0.f);
          hi = fmaxf(fmaf(sss[dd+1], hi, sss[128+dd+1]), 0.f);
          pv[j] = pk2(lo, hi);
        }
      }
      af[kk].u = v;
    }
  }
  f32x4 acc[8] = {};
  #pragma unroll
  for(int kk=0; kk<4; kk++){
    #pragma unroll
    for(int n=0;n<8;n++){
      int bbyte = (16*n + lr)*256 + kk*64 + lk*16;
      short8 b = *(const short8*)(sW + SWZ(bbyte));
      acc[n] = __builtin_amdgcn_mfma_f32_16x16x32_bf16(b, af[kk].s, acc[n], 0, 0, 0);
    }
  }
  if(gr < NN){
    float dv = dinv ? dinv[gr] : 1.f;
    #pragma unroll
    for(int n=0;n<8;n++){
      int chn = 16*n + lk*4;
      float b0=0.f,b1=0.f,b2=0.f,b3=0.f;
      if(bias){
        float4 bb = *(const float4*)(bias+chn);
        b0=bb.x; b1=bb.y; b2=bb.z; b3=bb.w;
      }
      float v0 = fmaf(acc[n][0], dv, b0);
      float v1 = fmaf(acc[n][1], dv, b1);
      float v2 = fmaf(acc[n][2], dv, b2);
      float v3 = fmaf(acc[n][3], dv, b3);
      uint2 o; o.x = pk2(v0,v1); o.y = pk2(v2,v3);
      *(uint2*)(outp + (size_t)gr*D + chn) = o;
    }
  }
}

// generic dual-mode GEMM (layers 2,3 and head)
__global__ __launch_bounds__(256) void k_mm(const unsigned short* __restrict__ in,
    const unsigned short* __restrict__ wTa, const unsigned short* __restrict__ wTb,
    unsigned short* __restrict__ outa, unsigned short* __restrict__ outb,
    const float* __restrict__ gpart, const float* __restrict__ g, const float* __restrict__ be,
    const float* __restrict__ dinv, const float* __restrict__ biasA, int halfGrid){
  int bid = blockIdx.x;
  bool second = bid >= halfGrid;
  int rb = (second ? bid-halfGrid : bid)*64;
  mm_body(rb, in, nullptr, second ? wTb : wTa, second ? outb : outa,
          gpart, g, be, dinv, second ? nullptr : biasA);
}

// fused CSR-fill + layer-1 GEMM (independent work, one dispatch)
__global__ __launch_bounds__(256) void k_fillmm(const int* __restrict__ src0,
    const int* __restrict__ dst0, const int* __restrict__ rowptr, int* __restrict__ cur,
    int* __restrict__ csr_src, int2* __restrict__ csr_de,
    const float* __restrict__ x, const unsigned short* __restrict__ w1T,
    unsigned short* __restrict__ U16, const float* __restrict__ dinv){
  int bid = blockIdx.x;
  if(bid < FB){
    int e = bid*256 + threadIdx.x;
    if(e<NE){
      int d = dst0[e];
      int pos = atomicAdd(&cur[d],1);
      int slot = rowptr[d]+pos;
      csr_src[slot] = src0[e];
      csr_de[slot] = make_int2(d, e);
    }
  } else {
    mm_body((bid-FB)*64, nullptr, x, w1T, U16, nullptr, nullptr, nullptr, dinv, nullptr);
  }
}

// ---------- gather + fused BN stats ----------
__global__ __launch_bounds__(256) void k_gather16(const unsigned short* __restrict__ U,
    const int* __restrict__ rowptr, const int* __restrict__ csr_src,
    const float* __restrict__ dinv, unsigned short* __restrict__ outp,
    float* __restrict__ gpart){
  __shared__ float sS[4][128], sQ[4][128];
  int t = threadIdx.x;
  int wv = t>>6, l = t&63;
  int node = blockIdx.x*4 + wv;   // grid exact: 12500*4 = NN
  const unsigned* U32 = (const unsigned*)U;
  unsigned u = U32[(size_t)node*64 + l];
  float a0 = bf2f(u & 0xFFFFu);
  float a1 = __uint_as_float(u & 0xFFFF0000u);
  int s = rowptr[node], e = rowptr[node+1];
  for(int base=s; base<e; base+=64){
    int idx = (base+l < e) ? csr_src[base+l] : 0;
    int n = min(64, e-base);
    for(int k=0;k<n;k++){
      int src = __shfl(idx, k, 64);
      unsigned v = U32[(size_t)src*64 + l];
      a0 += bf2f(v & 0xFFFFu);
      a1 += __uint_as_float(v & 0xFFFF0000u);
    }
  }
  float dv = dinv[node];
  float o0 = a0*dv, o1 = a1*dv;
  ((unsigned*)outp)[(size_t)node*64 + l] = pk2(o0, o1);
  sS[wv][2*l]   = o0;    sS[wv][2*l+1] = o1;
  sQ[wv][2*l]   = o0*o0; sQ[wv][2*l+1] = o1*o1;
  __syncthreads();
  if(t<128){
    float sv = sS[0][t]+sS[1][t]+sS[2][t]+sS[3][t];
    float qv = sQ[0][t]+sQ[1][t]+sQ[2][t]+sQ[3][t];
    float* gp = gpart + (size_t)(blockIdx.x & 63)*256;
    atomicAdd(&gp[t], sv);
    atomicAdd(&gp[128+t], qv);
  }
}

// ---------- edge head over dst-CSR-ordered edges ----------
__global__ __launch_bounds__(512) void k_edge(const int* __restrict__ csr_src,
    const int2* __restrict__ csr_de,
    const unsigned short* __restrict__ P16, const unsigned short* __restrict__ Q16,
    const unsigned short* __restrict__ wc2t, const float* __restrict__ bc2,
    const float* __restrict__ wc3, const float* __restrict__ bc3,
    float* __restrict__ out){
  __shared__ char sW[64*256];     // Wc2^T bf16 [64 cols][128 k], swizzled (16KB)
  __shared__ float sWc3[128];
  int t = threadIdx.x;
  int base = blockIdx.x*128;
  if(t<128) sWc3[t] = wc3[t];
  {
    const uint4* gw = (const uint4*)wc2t;
    #pragma unroll
    for(int i=0;i<2;i++){
      int G = t*2+i;                    // 512*2 = 1024 granules of 16B
      int byte = G*16;
      *(uint4*)(sW + SWZ(byte)) = gw[G];
    }
  }
  int w = t>>6, l = t&63;
  int lr = l&15, lk = l>>4;
  int e = base + 16*w + lr;
  int srcv = csr_src[e];
  int dstv = csr_de[e].x;
  const uint4* prow = (const uint4*)(P16 + (size_t)srcv*D);
  const uint4* qrow = (const uint4*)(Q16 + (size_t)dstv*D);
  uint4 pv[4], qv[4];
  #pragma unroll
  for(int kk=0;kk<4;kk++){ pv[kk] = prow[kk*4 + lk]; qv[kk] = qrow[kk*4 + lk]; }
  union { short8 s; uint4 u; } af[4];
  #pragma unroll
  for(int kk=0;kk<4;kk++){
    unsigned* pp = (unsigned*)&pv[kk];
    unsigned* qq = (unsigned*)&qv[kk];
    unsigned r[4];
    #pragma unroll
    for(int j=0;j<4;j++){
      float plo = bf2f(pp[j] & 0xFFFFu);
      float phi = __uint_as_float(pp[j] & 0xFFFF0000u);
      float qlo = bf2f(qq[j] & 0xFFFFu);
      float qhi = __uint_as_float(qq[j] & 0xFFFF0000u);
      r[j] = pk2(fmaxf(plo+qlo, 0.f), fmaxf(phi+qhi, 0.f));
    }
    af[kk].u = make_uint4(r[0], r[1], r[2], r[3]);
  }
  __syncthreads();
  f32x4 acc[4] = {{0.f,0.f,0.f,0.f},{0.f,0.f,0.f,0.f},{0.f,0.f,0.f,0.f},{0.f,0.f,0.f,0.f}};
  #pragma unroll
  for(int kk=0; kk<4; kk++){
    #pragma unroll
    for(int n=0;n<4;n++){
      int bbyte = (16*n + lr)*256 + kk*64 + lk*16;
      short8 bf = *(const short8*)(sW + SWZ(bbyte));
      acc[n] = __builtin_amdgcn_mfma_f32_16x16x32_bf16(af[kk].s, bf, acc[n], 0, 0, 0);
    }
  }
  float w30[4], w31[4], bb2[4];
  #pragma unroll
  for(int n=0;n<4;n++){
    int col = 16*n + lr;
    w30[n] = sWc3[col*2+0];
    w31[n] = sWc3[col*2+1];
    bb2[n] = bc2[col];
  }
  float c30 = bc3[0], c31 = bc3[1];
  #pragma unroll
  for(int reg=0; reg<4; reg++){
    float s0=0.f, s1=0.f;
    #pragma unroll
    for(int n=0;n<4;n++){
      float z = fmaxf(acc[n][reg] + bb2[n], 0.f);
      s0 = fmaf(z, w30[n], s0);
      s1 = fmaf(z, w31[n], s1);
    }
    #pragma unroll
    for(int off=1; off<16; off<<=1){
      s0 += __shfl_xor(s0, off, 64);
      s1 += __shfl_xor(s1, off, 64);
    }
    if(lr==0){
      int eid = csr_de[base + 16*w + lk*4 + reg].y;
      float2 res; res.x = s0 + c30; res.y = s1 + c31;
      *(float2*)(out + (size_t)eid*2) = res;
    }
  }
}

extern "C" void kernel_launch(void* const* d_in, const int* in_sizes, int n_in,
                              void* d_out, int out_size, void* d_ws, size_t ws_size,
                              hipStream_t stream) {
  const float* x   = (const float*)d_in[0];
  const int* ei    = (const int*)d_in[1];
  const int* src0  = ei;
  const int* dst0  = ei + NE;
  const float* W1  = (const float*)d_in[2];
  const float* W2  = (const float*)d_in[4];
  const float* W3  = (const float*)d_in[6];
  const float* g1  = (const float*)d_in[8];
  const float* be1 = (const float*)d_in[9];
  const float* g2  = (const float*)d_in[10];
  const float* be2 = (const float*)d_in[11];
  const float* g3  = (const float*)d_in[12];
  const float* be3 = (const float*)d_in[13];
  const float* Wc1 = (const float*)d_in[14];
  const float* bc1 = (const float*)d_in[15];
  const float* Wc2 = (const float*)d_in[16];
  const float* bc2 = (const float*)d_in[17];
  const float* Wc3 = (const float*)d_in[18];
  const float* bc3 = (const float*)d_in[19];
  float* out = (float*)d_out;

  char* ws = (char*)d_ws;
  size_t off = 0;
  auto alloc = [&](size_t bytes) -> void* {
    void* p = ws + off;
    off += (bytes + 511) & ~(size_t)511;
    return p;
  };
  // cnt (padded 200704) + gpart1..3 (3x65536) covered by one memset
  int*   cnt     = (int*)alloc(NN*sizeof(int));          // 200704 padded
  float* gpart1  = (float*)alloc(64*256*sizeof(float));  // 65536
  float* gpart2  = (float*)alloc(64*256*sizeof(float));
  float* gpart3  = (float*)alloc(64*256*sizeof(float));
  int*   rowptr  = (int*)alloc((NN+1)*sizeof(int));
  int*   bsum    = (int*)alloc(256*sizeof(int));
  int*   csr_src = (int*)alloc(NE*sizeof(int));
  int2*  csr_de  = (int2*)alloc(NE*sizeof(int2));
  float* dinv    = (float*)alloc(NN*sizeof(float));
  unsigned short* U16 = (unsigned short*)alloc((size_t)NN*D*2);  // also P
  unsigned short* H16 = (unsigned short*)alloc((size_t)NN*D*2);
  unsigned short* Q16 = (unsigned short*)alloc((size_t)NN*D*2);
  unsigned short* w1T  = (unsigned short*)alloc(128*128*2);
  unsigned short* w2T  = (unsigned short*)alloc(128*128*2);
  unsigned short* w3T  = (unsigned short*)alloc(128*128*2);
  unsigned short* wc1aT= (unsigned short*)alloc(128*128*2);
  unsigned short* wc1bT= (unsigned short*)alloc(128*128*2);
  unsigned short* wc2T = (unsigned short*)alloc(64*128*2);

  // one memset covers cnt (200704) + gpart1..3 (196608)
  hipMemsetAsync(cnt, 0, 200704 + 3*65536, stream);
  k_histprep<<<MMB, 256, 0, stream>>>(dst0, cnt, W1, W2, W3, Wc1, Wc2,
                                      w1T, w2T, w3T, wc1aT, wc1bT, wc2T);
  k_scanA<<<NBLK, 256, 0, stream>>>(cnt, bsum);
  k_scanC<<<NBLK, 256, 0, stream>>>(cnt, bsum, rowptr, dinv, cnt);

  const int GB = NN/4;   // 12500

  // fused CSR-fill + layer-1 GEMM (independent after scanC)
  k_fillmm<<<FB + MMB, 256, 0, stream>>>(src0, dst0, rowptr, cnt, csr_src, csr_de,
                                         x, w1T, U16, dinv);
  k_gather16<<<GB, 256, 0, stream>>>(U16, rowptr, csr_src, dinv, H16, gpart1);
  // layer 2 (BN1 derived in-block from gpart1)
  k_mm<<<MMB, 256, 0, stream>>>(H16, w2T, w2T, U16, U16,
                                gpart1, g1, be1, dinv, nullptr, MMB);
  k_gather16<<<GB, 256, 0, stream>>>(U16, rowptr, csr_src, dinv, H16, gpart2);
  // layer 3
  k_mm<<<MMB, 256, 0, stream>>>(H16, w3T, w3T, U16, U16,
                                gpart2, g2, be2, dinv, nullptr, MMB);
  k_gather16<<<GB, 256, 0, stream>>>(U16, rowptr, csr_src, dinv, H16, gpart3);

  // head projections (dual): P = bnrelu(H)@Wc1_top + bc1 ; Q = bnrelu(H)@Wc1_bot
  k_mm<<<2*MMB, 256, 0, stream>>>(H16, wc1aT, wc1bT, U16, Q16,
                                  gpart3, g3, be3, nullptr, bc1, MMB);

  // edge MLP over CSR-ordered edges
  k_edge<<<NE/128, 512, 0, stream>>>(csr_src, csr_de, U16, Q16, wc2T,
                                     bc2, Wc3, bc3, out);
}